// Round 7
// baseline (89.784 us; speedup 1.0000x reference)
//
#include <hip/hip_runtime.h>

#define NCAPS 1152
#define KD 8
#define JD 10
#define DD 16
#define BATCH 512
#define BTILE 64

typedef float f32x4 __attribute__((ext_vector_type(4)));

// out[b,n,j,d] = sum_k W[n,j,d,k] * pc[b,n,k],  pc = squash(x[b,n,:])
// R3 structure (73.7us): grid dim3(1152,8), block 320 = 8 batch-groups x 40
// (j,dq) combos, W in registers, pc tile in LDS.
// SINGLE CHANGE vs R3: regular cached stores instead of nontemporal
// (L2 write-combining path vs NT direct-to-HBM ablation).
__global__ __launch_bounds__(320) void caps_kernel(
    const float* __restrict__ x,   // [512, 1152*8]
    const float* __restrict__ W,   // [1152,10,16,8]
    float* __restrict__ out)       // [512,1152,10,16]
{
    const int n  = blockIdx.x;   // 0..1151
    const int bb = blockIdx.y;   // 0..7
    const int t  = threadIdx.x;  // 0..319

    __shared__ float pcs[BTILE][KD];   // squashed primary caps for this tile

    // ---- squash: one thread per batch row (first wave) ----
    if (t < BTILE) {
        int b = bb * BTILE + t;
        const float* xp = x + (size_t)b * (NCAPS * KD) + n * KD;
        float4 v0 = *(const float4*)(xp);
        float4 v1 = *(const float4*)(xp + 4);
        float sq = v0.x * v0.x + v0.y * v0.y + v0.z * v0.z + v0.w * v0.w
                 + v1.x * v1.x + v1.y * v1.y + v1.z * v1.z + v1.w * v1.w;
        float scale = sq / ((1.0f + sq) * sqrtf(sq + 1e-7f));
        pcs[t][0] = v0.x * scale;
        pcs[t][1] = v0.y * scale;
        pcs[t][2] = v0.z * scale;
        pcs[t][3] = v0.w * scale;
        pcs[t][4] = v1.x * scale;
        pcs[t][5] = v1.y * scale;
        pcs[t][6] = v1.z * scale;
        pcs[t][7] = v1.w * scale;
    }

    // ---- load this thread's W fragment into registers (L2-resident per XCD) ----
    const int c  = t % 40;       // (j,dq) combo
    const int g  = t / 40;       // batch group 0..7
    const int j  = c >> 2;
    const int dq = c & 3;
    const float* wp = W + (size_t)n * (JD * DD * KD) + j * (DD * KD) + dq * 4 * KD;
    float4 wA0 = *(const float4*)(wp + 0);
    float4 wB0 = *(const float4*)(wp + 4);
    float4 wA1 = *(const float4*)(wp + 8);
    float4 wB1 = *(const float4*)(wp + 12);
    float4 wA2 = *(const float4*)(wp + 16);
    float4 wB2 = *(const float4*)(wp + 20);
    float4 wA3 = *(const float4*)(wp + 24);
    float4 wB3 = *(const float4*)(wp + 28);

    __syncthreads();

    // ---- 8 batches per thread: broadcast pc from LDS, 32 FMA, 1 store ----
    #pragma unroll
    for (int i = 0; i < 8; ++i) {
        int bl = g * 8 + i;
        float4 p0 = *(const float4*)&pcs[bl][0];
        float4 p1 = *(const float4*)&pcs[bl][4];

        f32x4 acc;
        acc.x = wA0.x*p0.x + wA0.y*p0.y + wA0.z*p0.z + wA0.w*p0.w
              + wB0.x*p1.x + wB0.y*p1.y + wB0.z*p1.z + wB0.w*p1.w;
        acc.y = wA1.x*p0.x + wA1.y*p0.y + wA1.z*p0.z + wA1.w*p0.w
              + wB1.x*p1.x + wB1.y*p1.y + wB1.z*p1.z + wB1.w*p1.w;
        acc.z = wA2.x*p0.x + wA2.y*p0.y + wA2.z*p0.z + wA2.w*p0.w
              + wB2.x*p1.x + wB2.y*p1.y + wB2.z*p1.z + wB2.w*p1.w;
        acc.w = wA3.x*p0.x + wA3.y*p0.y + wA3.z*p0.z + wA3.w*p0.w
              + wB3.x*p1.x + wB3.y*p1.y + wB3.z*p1.z + wB3.w*p1.w;

        int b = bb * BTILE + bl;
        size_t off = (((size_t)b * NCAPS + n) * JD + j) * DD + (dq << 2);
        *(f32x4*)(out + off) = acc;
    }
}

extern "C" void kernel_launch(void* const* d_in, const int* in_sizes, int n_in,
                              void* d_out, int out_size, void* d_ws, size_t ws_size,
                              hipStream_t stream) {
    const float* x = (const float*)d_in[0];
    const float* W = (const float*)d_in[1];
    float* out = (float*)d_out;
    dim3 grid(NCAPS, BATCH / BTILE);
    caps_kernel<<<grid, 320, 0, stream>>>(x, W, out);
}

// Round 8
// 73.652 us; speedup vs baseline: 1.2190x; 1.2190x over previous
//
#include <hip/hip_runtime.h>

#define NCAPS 1152
#define KD 8
#define JD 10
#define DD 16
#define BATCH 512
#define BTILE 64

typedef float f32x4 __attribute__((ext_vector_type(4)));

// out[b,n,j,d] = sum_k W[n,j,d,k] * pc[b,n,k],  pc = squash(x[b,n,:])
// Block: 320 threads = 8 batch-groups x 40 (j,dq) combos. W held in registers.
// This is the R3 kernel (73.7us) — best of 7 rounds. Ablations that LOST:
//   n->XCD remaps (85.2 / 78.7 / 79.0us): default linear dispatch already
//     gives same-bb concurrency + contiguous write-row fill + L2-resident W.
//   8n x 32b restructure w/ 1KB wave stores (78.7us): store segmentation
//     was not the bottleneck; schedule perturbation cost more.
//   cached stores (89.8us): NT direct-to-HBM is right for a 377MB stream.
__global__ __launch_bounds__(320) void caps_kernel(
    const float* __restrict__ x,   // [512, 1152*8]
    const float* __restrict__ W,   // [1152,10,16,8]
    float* __restrict__ out)       // [512,1152,10,16]
{
    const int n  = blockIdx.x;   // 0..1151
    const int bb = blockIdx.y;   // 0..7
    const int t  = threadIdx.x;  // 0..319

    __shared__ float pcs[BTILE][KD];   // squashed primary caps for this tile

    // ---- squash: one thread per batch row (first wave) ----
    if (t < BTILE) {
        int b = bb * BTILE + t;
        const float* xp = x + (size_t)b * (NCAPS * KD) + n * KD;
        float4 v0 = *(const float4*)(xp);
        float4 v1 = *(const float4*)(xp + 4);
        float sq = v0.x * v0.x + v0.y * v0.y + v0.z * v0.z + v0.w * v0.w
                 + v1.x * v1.x + v1.y * v1.y + v1.z * v1.z + v1.w * v1.w;
        float scale = sq / ((1.0f + sq) * sqrtf(sq + 1e-7f));
        pcs[t][0] = v0.x * scale;
        pcs[t][1] = v0.y * scale;
        pcs[t][2] = v0.z * scale;
        pcs[t][3] = v0.w * scale;
        pcs[t][4] = v1.x * scale;
        pcs[t][5] = v1.y * scale;
        pcs[t][6] = v1.z * scale;
        pcs[t][7] = v1.w * scale;
    }

    // ---- load this thread's W fragment into registers (L2-resident per XCD) ----
    const int c  = t % 40;       // (j,dq) combo
    const int g  = t / 40;       // batch group 0..7
    const int j  = c >> 2;
    const int dq = c & 3;
    const float* wp = W + (size_t)n * (JD * DD * KD) + j * (DD * KD) + dq * 4 * KD;
    float4 wA0 = *(const float4*)(wp + 0);
    float4 wB0 = *(const float4*)(wp + 4);
    float4 wA1 = *(const float4*)(wp + 8);
    float4 wB1 = *(const float4*)(wp + 12);
    float4 wA2 = *(const float4*)(wp + 16);
    float4 wB2 = *(const float4*)(wp + 20);
    float4 wA3 = *(const float4*)(wp + 24);
    float4 wB3 = *(const float4*)(wp + 28);

    __syncthreads();

    // ---- 8 batches per thread: broadcast pc from LDS, 32 FMA, 1 store ----
    #pragma unroll
    for (int i = 0; i < 8; ++i) {
        int bl = g * 8 + i;
        float4 p0 = *(const float4*)&pcs[bl][0];
        float4 p1 = *(const float4*)&pcs[bl][4];

        f32x4 acc;
        acc.x = wA0.x*p0.x + wA0.y*p0.y + wA0.z*p0.z + wA0.w*p0.w
              + wB0.x*p1.x + wB0.y*p1.y + wB0.z*p1.z + wB0.w*p1.w;
        acc.y = wA1.x*p0.x + wA1.y*p0.y + wA1.z*p0.z + wA1.w*p0.w
              + wB1.x*p1.x + wB1.y*p1.y + wB1.z*p1.z + wB1.w*p1.w;
        acc.z = wA2.x*p0.x + wA2.y*p0.y + wA2.z*p0.z + wA2.w*p0.w
              + wB2.x*p1.x + wB2.y*p1.y + wB2.z*p1.z + wB2.w*p1.w;
        acc.w = wA3.x*p0.x + wA3.y*p0.y + wA3.z*p0.z + wA3.w*p0.w
              + wB3.x*p1.x + wB3.y*p1.y + wB3.z*p1.z + wB3.w*p1.w;

        int b = bb * BTILE + bl;
        size_t off = (((size_t)b * NCAPS + n) * JD + j) * DD + (dq << 2);
        __builtin_nontemporal_store(acc, (f32x4*)(out + off));
    }
}

extern "C" void kernel_launch(void* const* d_in, const int* in_sizes, int n_in,
                              void* d_out, int out_size, void* d_ws, size_t ws_size,
                              hipStream_t stream) {
    const float* x = (const float*)d_in[0];
    const float* W = (const float*)d_in[1];
    float* out = (float*)d_out;
    dim3 grid(NCAPS, BATCH / BTILE);
    caps_kernel<<<grid, 320, 0, stream>>>(x, W, out);
}